// Round 7
// baseline (377.295 us; speedup 1.0000x reference)
//
#include <hip/hip_runtime.h>
#include <math.h>

#define Bsz 4
#define Sq  2048
#define Eq  1024
#define Hh  16
#define DHd 64
#define Kb  9
#define STR 72   // LDS row stride (halves): 144 B = 9x16B (b128-aligned), 2-way banks
#define LOG2E 1.4426950408889634f

typedef _Float16 f16;
typedef __attribute__((ext_vector_type(2))) _Float16 fh2;  // packed pair (b32 store)
typedef __attribute__((ext_vector_type(8))) _Float16 fh8;  // MFMA A/B frag (4 VGPRs)
typedef __attribute__((ext_vector_type(4))) float fx4;     // MFMA C/D frag

// ---------------------------------------------------------------------------
// passage id + column value (searchsorted semantics).
// colval is PRE-SCALED by log2e: mask exp computed as exp2(s*log2e + mvl2).
// ---------------------------------------------------------------------------
__global__ void pid_kernel(const int* __restrict__ bnd, const float* __restrict__ rel,
                           int* __restrict__ pidq, float* __restrict__ colval) {
  int idx = blockIdx.x * blockDim.x + threadIdx.x;
  if (idx >= Bsz * Sq) return;
  int b = idx >> 11;
  int s = idx & (Sq - 1);
  int j = -1;
#pragma unroll
  for (int t = 0; t < Kb; ++t) {
    if (bnd[b * Kb + t] <= s) j = t;
  }
  pidq[idx] = j;
  colval[idx] = ((j >= 0 && j < Kb - 1) ? rel[b * (Kb - 1) + j] : 1.0f) * LOG2E;
}

// ---------------------------------------------------------------------------
// fp32 -> fp16 cast, 8 elems/thread
// ---------------------------------------------------------------------------
__global__ __launch_bounds__(256) void cvt_hs(const float* __restrict__ x,
                                              f16* __restrict__ xo) {
  int i = (blockIdx.x * blockDim.x + threadIdx.x) * 8;
  float4 a = *(const float4*)&x[i];
  float4 b = *(const float4*)&x[i + 4];
  fh8 o;
  o[0] = (f16)a.x; o[1] = (f16)a.y; o[2] = (f16)a.z; o[3] = (f16)a.w;
  o[4] = (f16)b.x; o[5] = (f16)b.y; o[6] = (f16)b.z; o[7] = (f16)b.w;
  *(fh8*)&xo[i] = o;
}

// ---------------------------------------------------------------------------
// fp16 MFMA GEMM: C = A * B^T + bias.  A:(M,K) fp16, B:(N,K) fp16 (pre-cvt).
// 128x128x64 tile, 4 waves 2x2, 16x16x32 MFMA. Full 128-row staging coverage.
// MODE 0: Cp[m*N+n] = acc + bias (fp32)
// MODE 1: n<1024 -> q fp16 scaled 0.125 (B,H,S,DH); n<2048 -> k (B,H,S,DH);
//         else   -> vt fp16 TRANSPOSED (B,H,DH,S)
// ---------------------------------------------------------------------------
template <int MODE>
__global__ __launch_bounds__(256) void gemm_f16(
    const f16* __restrict__ A, const f16* __restrict__ Bf,
    const float* __restrict__ bias, float* __restrict__ Cp,
    int M, int N, int Kd,
    f16* __restrict__ qo, f16* __restrict__ ko, f16* __restrict__ vto) {
  __shared__ __align__(16) f16 Ash[128 * STR];
  __shared__ __align__(16) f16 Bsh[128 * STR];

  const int tid = threadIdx.x;
  const int lane = tid & 63, w = tid >> 6;
  const int wm = w >> 1, wn = w & 1;
  const int q16 = lane & 15, quad = lane >> 4;
  const int m_blk = blockIdx.y * 128, n_blk = blockIdx.x * 128;

  fx4 acc[4][4];
#pragma unroll
  for (int mt = 0; mt < 4; ++mt)
#pragma unroll
    for (int nt = 0; nt < 4; ++nt)
#pragma unroll
      for (int r = 0; r < 4; ++r) acc[mt][nt][r] = 0.f;

  const int sr = tid >> 2, sc = (tid & 3) * 16;

  for (int k0 = 0; k0 < Kd; k0 += 64) {
    __syncthreads();
#pragma unroll
    for (int h = 0; h < 2; ++h) {  // rows sr and sr+64: full 128-row coverage
      const int r = sr + h * 64;
      const f16* ga = &A[(size_t)(m_blk + r) * Kd + k0 + sc];
      *(fh8*)&Ash[r * STR + sc]     = *(const fh8*)&ga[0];
      *(fh8*)&Ash[r * STR + sc + 8] = *(const fh8*)&ga[8];
      const f16* gb = &Bf[(size_t)(n_blk + r) * Kd + k0 + sc];
      *(fh8*)&Bsh[r * STR + sc]     = *(const fh8*)&gb[0];
      *(fh8*)&Bsh[r * STR + sc + 8] = *(const fh8*)&gb[8];
    }
    __syncthreads();

#pragma unroll
    for (int ks = 0; ks < 2; ++ks) {
      fh8 af[4], bfr[4];
#pragma unroll
      for (int mt = 0; mt < 4; ++mt)
        af[mt] = *(const fh8*)&Ash[(wm * 64 + mt * 16 + q16) * STR + ks * 32 + quad * 8];
#pragma unroll
      for (int nt = 0; nt < 4; ++nt)
        bfr[nt] = *(const fh8*)&Bsh[(wn * 64 + nt * 16 + q16) * STR + ks * 32 + quad * 8];
#pragma unroll
      for (int nt = 0; nt < 4; ++nt)
#pragma unroll
        for (int mt = 0; mt < 4; ++mt)
          acc[mt][nt] = __builtin_amdgcn_mfma_f32_16x16x32_f16(af[mt], bfr[nt], acc[mt][nt], 0, 0, 0);
    }
  }

  float bsv[4];
#pragma unroll
  for (int nt = 0; nt < 4; ++nt) bsv[nt] = bias[n_blk + wn * 64 + nt * 16 + q16];

  if (MODE == 0) {
#pragma unroll
    for (int mt = 0; mt < 4; ++mt)
#pragma unroll
      for (int r = 0; r < 4; ++r) {
        int row = m_blk + wm * 64 + mt * 16 + quad * 4 + r;
#pragma unroll
        for (int nt = 0; nt < 4; ++nt) {
          int col = n_blk + wn * 64 + nt * 16 + q16;
          Cp[(size_t)row * N + col] = acc[mt][nt][r] + bsv[nt];
        }
      }
  } else {
    const int n0 = n_blk + wn * 64;  // 64-aligned -> which/hd wave-uniform
    const int which = n0 >> 10;
    const int hd = (n0 & 1023) >> 6;
    const float scale = (which == 0) ? 0.125f : 1.0f;
#pragma unroll
    for (int mt = 0; mt < 4; ++mt)
#pragma unroll
      for (int r = 0; r < 4; ++r) {
        int m = m_blk + wm * 64 + mt * 16 + quad * 4 + r;
        int b = m >> 11, s = m & (Sq - 1);
#pragma unroll
        for (int nt = 0; nt < 4; ++nt) {
          int d = nt * 16 + q16;
          float x = (acc[mt][nt][r] + bsv[nt]) * scale;
          if (which == 2) {  // V transposed: (B,H,DH,S)
            vto[(((size_t)(b * Hh + hd)) * DHd + d) * Sq + s] = (f16)x;
          } else {
            f16* dst = (which == 0) ? qo : ko;
            dst[(((size_t)(b * Hh + hd)) * Sq + s) * DHd + d] = (f16)x;
          }
        }
      }
  }
}

// ---------------------------------------------------------------------------
// Flash attention, single-fp16, TRANSPOSED scores: S_T = K*Q^T (swap MFMA
// operands; identical loads). C-layout then gives each lane a q-row with 4
// CONTIGUOUS k-cols -> P packed in-lane (fh2 = v_cvt_pkrtz) and written b32;
// row-sums accumulate in registers (no ones-MFMA, no in-loop shuffles).
// No-max softmax (scores bounded; validated R5). Block: 4 waves x 32 q-rows.
// ---------------------------------------------------------------------------
__global__ __launch_bounds__(256, 3) void attn_f16(
    const f16* __restrict__ Qf, const f16* __restrict__ Kf,
    const f16* __restrict__ Vt, const int* __restrict__ pidq,
    const float* __restrict__ colval, f16* __restrict__ attf) {
  const int qb = blockIdx.x, hd = blockIdx.y, b = blockIdx.z;
  const int bh = b * Hh + hd;
  const int tid = threadIdx.x, lane = tid & 63, w = tid >> 6;
  const int q16 = lane & 15, quad = lane >> 4;

  __shared__ __align__(16) f16 Ks[64 * STR];
  __shared__ __align__(16) f16 Vs[64 * STR];
  __shared__ __align__(16) f16 Ps[4][32 * STR];  // per-wave, rows = q-rows

  const size_t qkbase = (size_t)bh * Sq * DHd;  // (b,h,s,d)
  const size_t vtbase = (size_t)bh * DHd * Sq;  // (b,h,d,s)

  // Q frags in registers (B-operand for QK-T; same layout as before)
  fh8 qf[2][2];
#pragma unroll
  for (int mt = 0; mt < 2; ++mt)
#pragma unroll
    for (int ks = 0; ks < 2; ++ks)
      qf[mt][ks] = *(const fh8*)&Qf[qkbase +
          (size_t)(qb * 128 + w * 32 + mt * 16 + q16) * DHd + ks * 32 + quad * 8];

  // per-lane q-row passage id (row = mt*16 + q16)
  int pqr[2];
#pragma unroll
  for (int mt = 0; mt < 2; ++mt)
    pqr[mt] = pidq[b * Sq + qb * 128 + w * 32 + mt * 16 + q16];

  fx4 o_acc[2][4];
  float lsum[2] = {0.f, 0.f};
#pragma unroll
  for (int mt = 0; mt < 2; ++mt)
#pragma unroll
    for (int dt = 0; dt < 4; ++dt)
#pragma unroll
      for (int r = 0; r < 4; ++r) o_acc[mt][dt][r] = 0.f;

  for (int kt = 0; kt < 32; ++kt) {
    __syncthreads();  // prior iter's frag reads done before restage
    {
      int n = tid >> 2, c = (tid & 3) * 16;
      size_t gk = qkbase + (size_t)(kt * 64 + n) * DHd + c;
      *(fh8*)&Ks[n * STR + c]     = *(const fh8*)&Kf[gk];
      *(fh8*)&Ks[n * STR + c + 8] = *(const fh8*)&Kf[gk + 8];
      size_t gv = vtbase + (size_t)n * Sq + kt * 64 + c;  // row n = d
      *(fh8*)&Vs[n * STR + c]     = *(const fh8*)&Vt[gv];
      *(fh8*)&Vs[n * STR + c + 8] = *(const fh8*)&Vt[gv + 8];
    }
    __syncthreads();

    // ---- S_T = K * Q^T : sacc[ct][mt], C-elem = S[q=mt*16+q16][k=ct*16+quad*4+r]
    fx4 sacc[4][2];
#pragma unroll
    for (int ct = 0; ct < 4; ++ct)
#pragma unroll
      for (int mt = 0; mt < 2; ++mt)
#pragma unroll
        for (int r = 0; r < 4; ++r) sacc[ct][mt][r] = 0.f;

#pragma unroll
    for (int ks = 0; ks < 2; ++ks)
#pragma unroll
      for (int ct = 0; ct < 4; ++ct) {
        fh8 kf8 = *(const fh8*)&Ks[(ct * 16 + q16) * STR + ks * 32 + quad * 8];
#pragma unroll
        for (int mt = 0; mt < 2; ++mt)
          sacc[ct][mt] = __builtin_amdgcn_mfma_f32_16x16x32_f16(kf8, qf[mt][ks], sacc[ct][mt], 0, 0, 0);
      }

    // ---- per-lane column attrs: cols kt*64 + ct*16 + quad*4 + {0..3}
    int4 p4[4]; float4 c4[4];
#pragma unroll
    for (int ct = 0; ct < 4; ++ct) {
      int c0 = kt * 64 + ct * 16 + quad * 4;
      p4[ct] = *(const int4*)&pidq[b * Sq + c0];
      c4[ct] = *(const float4*)&colval[b * Sq + c0];  // pre-scaled by log2e
    }

    // ---- softmax numerators + in-lane pack + Ps write (b32 pairs) ----
#pragma unroll
    for (int mt = 0; mt < 2; ++mt) {
      const int rq = pqr[mt];
      const bool isq = rq < 0;
      const int prow = (mt * 16 + q16) * STR;
#pragma unroll
      for (int ct = 0; ct < 4; ++ct) {
        float pr[4];
        const int pv[4] = {p4[ct].x, p4[ct].y, p4[ct].z, p4[ct].w};
        const float cl[4] = {c4[ct].x, c4[ct].y, c4[ct].z, c4[ct].w};
#pragma unroll
        for (int r = 0; r < 4; ++r) {
          int pc = ((unsigned)pv[r] < 8u) ? pv[r] : -2;
          float mvl2 = isq ? cl[r] : ((rq == pc) ? LOG2E : 0.f);
          pr[r] = exp2f(fmaf(sacc[ct][mt][r], LOG2E, mvl2));
        }
        lsum[mt] += (pr[0] + pr[1]) + (pr[2] + pr[3]);
        fh2 pk0, pk1;
        pk0[0] = (f16)pr[0]; pk0[1] = (f16)pr[1];
        pk1[0] = (f16)pr[2]; pk1[1] = (f16)pr[3];
        *(fh2*)&Ps[w][prow + ct * 16 + quad * 4]     = pk0;
        *(fh2*)&Ps[w][prow + ct * 16 + quad * 4 + 2] = pk1;
      }
    }

    // ---- O += P * V  (A = P from Ps, B = V from Vs) ----
#pragma unroll
    for (int ks2 = 0; ks2 < 2; ++ks2) {
      fh8 pf[2];
#pragma unroll
      for (int mt = 0; mt < 2; ++mt)
        pf[mt] = *(const fh8*)&Ps[w][(mt * 16 + q16) * STR + ks2 * 32 + quad * 8];
#pragma unroll
      for (int dt = 0; dt < 4; ++dt) {
        fh8 vf = *(const fh8*)&Vs[(dt * 16 + q16) * STR + ks2 * 32 + quad * 8];
#pragma unroll
        for (int mt = 0; mt < 2; ++mt)
          o_acc[mt][dt] = __builtin_amdgcn_mfma_f32_16x16x32_f16(pf[mt], vf, o_acc[mt][dt], 0, 0, 0);
      }
    }
  }

  // epilogue: full row-sum = reduce over quads (lanes differ in bits 4-5);
  // O rows are quad*4+r, whose l lives in lane q16==quad*4+r -> shfl fetch.
#pragma unroll
  for (int mt = 0; mt < 2; ++mt) {
    float l = lsum[mt];
    l += __shfl_xor(l, 16);
    l += __shfl_xor(l, 32);
    float inv = 1.0f / l;
#pragma unroll
    for (int r = 0; r < 4; ++r) {
      float invr = __shfl(inv, quad * 4 + r);
      int qg = qb * 128 + w * 32 + mt * 16 + quad * 4 + r;
      size_t base = ((size_t)(b * Sq + qg)) * Eq + hd * 64;
#pragma unroll
      for (int dt = 0; dt < 4; ++dt)
        attf[base + dt * 16 + q16] = (f16)(o_acc[mt][dt][r] * invr);
    }
  }
}

// ---------------------------------------------------------------------------
extern "C" void kernel_launch(void* const* d_in, const int* in_sizes, int n_in,
                              void* d_out, int out_size, void* d_ws, size_t ws_size,
                              hipStream_t stream) {
  const float* hs = (const float*)d_in[0];
  const float* rel = (const float*)d_in[1];
  const int* bnd = (const int*)d_in[2];
  const float* wi = (const float*)d_in[3];
  const float* bi = (const float*)d_in[4];
  const float* wo = (const float*)d_in[5];
  const float* bo = (const float*)d_in[6];
  float* out = (float*)d_out;

  const size_t NQ = (size_t)Bsz * Hh * Sq * DHd;  // 8,388,608 (== B*S*E)
  const size_t NWI = (size_t)3 * Eq * Eq;         // 3,145,728
  const size_t NWO = (size_t)Eq * Eq;             // 1,048,576
  char* p = (char*)d_ws;
  f16* qf = (f16*)p;   p += NQ * 2;
  f16* kf = (f16*)p;   p += NQ * 2;
  f16* vt = (f16*)p;   p += NQ * 2;
  f16* hsf = (f16*)p;  p += NQ * 2;
  f16* attf = (f16*)p; p += NQ * 2;
  f16* wif = (f16*)p;  p += NWI * 2;
  f16* wof = (f16*)p;  p += NWO * 2;
  int* pidq = (int*)p; p += Bsz * Sq * 4;
  float* colv = (float*)p;
  // total ~92.4 MB < proven 134 MB footprint

  hipLaunchKernelGGL(pid_kernel, dim3((Bsz * Sq + 255) / 256), dim3(256), 0, stream,
                     bnd, rel, pidq, colv);
  hipLaunchKernelGGL(cvt_hs, dim3((int)(NQ / 2048)), dim3(256), 0, stream, hs, hsf);
  hipLaunchKernelGGL(cvt_hs, dim3((int)(NWI / 2048)), dim3(256), 0, stream, wi, wif);
  hipLaunchKernelGGL(cvt_hs, dim3((int)(NWO / 2048)), dim3(256), 0, stream, wo, wof);
  hipLaunchKernelGGL((gemm_f16<1>), dim3(24, 64), dim3(256), 0, stream,
                     hsf, wif, bi, (float*)nullptr, Bsz * Sq, 3 * Eq, Eq,
                     qf, kf, vt);
  hipLaunchKernelGGL(attn_f16, dim3(16, 16, 4), dim3(256), 0, stream,
                     qf, kf, vt, pidq, colv, attf);
  hipLaunchKernelGGL((gemm_f16<0>), dim3(8, 64), dim3(256), 0, stream,
                     attf, wof, bo, out, Bsz * Sq, Eq, Eq,
                     nullptr, nullptr, nullptr);
}